// Round 8
// baseline (512.100 us; speedup 1.0000x reference)
//
#include <hip/hip_runtime.h>
#include <cstdint>
#include <cstddef>

#define NTOT 6144
#define NDRUG 3072
#define NM (NTOT*64)

typedef __fp16 f16;
typedef __attribute__((ext_vector_type(2))) __fp16 f16x2;
typedef __attribute__((ext_vector_type(4))) __fp16 f16x4;
typedef __attribute__((ext_vector_type(8))) __fp16 f16x8;
typedef __attribute__((ext_vector_type(4))) float f32x4;

__device__ __forceinline__ f16x8 pack8(float4 a, float4 b){
  f16x2 p0 = __builtin_amdgcn_cvt_pkrtz(a.x, a.y);
  f16x2 p1 = __builtin_amdgcn_cvt_pkrtz(a.z, a.w);
  f16x2 p2 = __builtin_amdgcn_cvt_pkrtz(b.x, b.y);
  f16x2 p3 = __builtin_amdgcn_cvt_pkrtz(b.z, b.w);
  f16x4 lo = __builtin_shufflevector(p0, p1, 0, 1, 2, 3);
  f16x4 hi = __builtin_shufflevector(p2, p3, 0, 1, 2, 3);
  return __builtin_shufflevector(lo, hi, 0, 1, 2, 3, 4, 5, 6, 7);
}

// ------- Kernel 1: deg+proj producer, then split-K MFMA GEMM consumer -------
// grid 768 x 256thr. Block bx: (a) rowsum->norm + nfs^T for rows [8bx,8bx+8)
// (all within k-slice z = bx/96); (b) bump ready[z]; (c) spin until the 96
// producers of slice z are done; (d) GEMM tile (x=bx%96, z), depth-2 prefetch.
// All 768 blocks co-resident (LDS 36.9KB -> 4/CU cap, 1024 >= 768) so the
// per-slice spin cannot deadlock regardless of dispatch order.
__global__ __launch_bounds__(256, 3) void k_dg(const float* __restrict__ graph,
                                               const float* __restrict__ drug_f,
                                               const float* __restrict__ dis_f,
                                               const float* __restrict__ drug_w,
                                               const float* __restrict__ dis_w,
                                               float* __restrict__ norm,
                                               f16* __restrict__ nfst,
                                               float* __restrict__ part,
                                               unsigned* __restrict__ ready){
  __shared__ __align__(16) char smem[36864];
  const int tid = threadIdx.x;
  const int bx = blockIdx.x;
  const int wv = tid >> 6, j = tid & 63;

  // ---- (a) producer: degree + projection for 8 rows --------------------
  {
    float (*sx)[64]  = (float(*)[64])smem;
    float (*snf)[64] = (float(*)[64])(smem + 1024);
    for (int half = 0; half < 2; ++half){
      const int bi = bx*2 + half;
      const int row = bi*4 + wv;
      const float4* p = (const float4*)(graph + (size_t)row * NTOT);
      float s = 0.f;
      #pragma unroll
      for (int it = 0; it < 24; ++it) {
        float4 u = p[it*64 + j];
        s += (u.x + u.y) + (u.z + u.w);
      }
      #pragma unroll
      for (int off = 32; off; off >>= 1) s += __shfl_xor(s, off, 64);
      float nrm = rsqrtf(fmaxf(s, 1.0f));
      if (j == 0) norm[row] = nrm;

      const float* x; const float* W;
      if (row < NDRUG){ x = drug_f + (size_t)row*64; W = drug_w; }
      else            { x = dis_f + (size_t)(row-NDRUG)*64; W = dis_w; }
      sx[wv][j] = x[j];
      __syncthreads();
      float acc = 0.f;
      #pragma unroll 8
      for (int k = 0; k < 64; ++k) acc = fmaf(sx[wv][k], W[k*64+j], acc);
      snf[wv][j] = acc * nrm;
      __syncthreads();
      if (tid < 64){
        int c = tid;
        f16x4 pk = {(f16)snf[0][c], (f16)snf[1][c], (f16)snf[2][c], (f16)snf[3][c]};
        *(f16x4*)(nfst + (size_t)c*NTOT + bi*4) = pk;
      }
      __syncthreads();
    }
  }

  // ---- (b)+(c) per-slice ready handshake -------------------------------
  const int z = bx / 96;
  if (tid == 0){
    __threadfence();  // release: make nfst/norm visible across XCDs
    __hip_atomic_fetch_add(ready + z, 1u, __ATOMIC_ACQ_REL, __HIP_MEMORY_SCOPE_AGENT);
    while (__hip_atomic_load(ready + z, __ATOMIC_ACQUIRE, __HIP_MEMORY_SCOPE_AGENT) < 96u)
      __builtin_amdgcn_s_sleep(2);
    __threadfence();  // acquire
  }
  __syncthreads();

  // ---- (d) consumer: GEMM tile (x, z), depth-2 prefetch ----------------
  {
    typedef f16 (*TileP)[64][72];
    TileP sA = (TileP)smem;               // 2*64*72*2 = 18432 B
    TileP sB = (TileP)(smem + 18432);
    const int lane = tid & 63, w = tid >> 6;
    const int l15 = lane & 15, quad = lane >> 4;
    const int row0 = (bx % 96) * 64;
    const int kbase = z * 768;
    const int sr = tid >> 2, scg = (tid & 3) * 16;

    f32x4 acc[4] = {{0.f,0.f,0.f,0.f},{0.f,0.f,0.f,0.f},
                    {0.f,0.f,0.f,0.f},{0.f,0.f,0.f,0.f}};
    float4 aA0, aA1, aA2, aA3, aB0, aB1, aB2, aB3;
    f16x8 bA0, bA1, bB0, bB1;
    auto LOADA = [&](int kt){
      const float4* pa = (const float4*)(graph + (size_t)(row0 + sr)*NTOT + kbase + kt*64 + scg);
      aA0 = pa[0]; aA1 = pa[1]; aA2 = pa[2]; aA3 = pa[3];
      const f16* pb = nfst + (size_t)sr*NTOT + kbase + kt*64 + scg;
      bA0 = *(const f16x8*)pb; bA1 = *(const f16x8*)(pb + 8);
    };
    auto LOADB = [&](int kt){
      const float4* pa = (const float4*)(graph + (size_t)(row0 + sr)*NTOT + kbase + kt*64 + scg);
      aB0 = pa[0]; aB1 = pa[1]; aB2 = pa[2]; aB3 = pa[3];
      const f16* pb = nfst + (size_t)sr*NTOT + kbase + kt*64 + scg;
      bB0 = *(const f16x8*)pb; bB1 = *(const f16x8*)(pb + 8);
    };
    auto WRA = [&](int b){
      *(f16x8*)&sA[b][sr][scg]     = pack8(aA0, aA1);
      *(f16x8*)&sA[b][sr][scg + 8] = pack8(aA2, aA3);
      *(f16x8*)&sB[b][sr][scg]     = bA0;
      *(f16x8*)&sB[b][sr][scg + 8] = bA1;
    };
    auto WRB = [&](int b){
      *(f16x8*)&sA[b][sr][scg]     = pack8(aB0, aB1);
      *(f16x8*)&sA[b][sr][scg + 8] = pack8(aB2, aB3);
      *(f16x8*)&sB[b][sr][scg]     = bB0;
      *(f16x8*)&sB[b][sr][scg + 8] = bB1;
    };
    auto COMPUTE = [&](int b){
      #pragma unroll
      for (int k16 = 0; k16 < 4; ++k16){
        f16x4 af = *(const f16x4*)&sA[b][w*16 + l15][k16*16 + quad*4];
        #pragma unroll
        for (int nt = 0; nt < 4; ++nt){
          f16x4 bf = *(const f16x4*)&sB[b][nt*16 + l15][k16*16 + quad*4];
          acc[nt] = __builtin_amdgcn_mfma_f32_16x16x16f16(af, bf, acc[nt], 0, 0, 0);
        }
      }
    };
    LOADA(0); LOADB(1); WRA(0);
    for (int kt2 = 0; kt2 < 12; kt2 += 2){
      if (kt2 + 2 < 12) LOADA(kt2 + 2);
      __syncthreads();
      COMPUTE(0);
      WRB(1);
      if (kt2 + 3 < 12) LOADB(kt2 + 3);
      __syncthreads();
      COMPUTE(1);
      if (kt2 + 2 < 12) WRA(0);
    }
    float* dst = part + (size_t)z * NM;
    #pragma unroll
    for (int nt = 0; nt < 4; ++nt){
      #pragma unroll
      for (int r = 0; r < 4; ++r){
        int row = row0 + w*16 + quad*4 + r;
        dst[(size_t)row*64 + nt*16 + l15] = acc[nt][r];
      }
    }
  }
}

// ------- Kernel 2: finish + time-emb MLP + qkv (fused) -----------------------
// q pre-scaled by 0.25*log2(e) so attention can use native exp2.
__global__ __launch_bounds__(256) void k_node2(const float* __restrict__ part,
                                               const float* __restrict__ norm,
                                               const int* __restrict__ ts,
                                               const float* __restrict__ emb_w,
                                               const float* __restrict__ emb_b,
                                               const float* __restrict__ in_w,
                                               const float* __restrict__ in_b,
                                               const float* __restrict__ out_w,
                                               const float* __restrict__ out_b,
                                               const float* __restrict__ wq, const float* __restrict__ bq,
                                               const float* __restrict__ wk, const float* __restrict__ bk,
                                               const float* __restrict__ wvw, const float* __restrict__ bv,
                                               float* __restrict__ target,
                                               f16* __restrict__ qh, f16* __restrict__ kh,
                                               f16* __restrict__ vt){
  __shared__ float sx[4][80];    // [0..63]=target row, [64..79]=time emb
  __shared__ float sh[4][256];
  __shared__ float sa[4][64];    // aux row (LDS only)
  __shared__ float sv[4][64];    // v row (for transpose)
  int wv = threadIdx.x>>6, j = threadIdx.x&63;
  int row = blockIdx.x*4 + wv;

  float t = 0.f;
  #pragma unroll
  for (int p = 0; p < 8; ++p) t += part[(size_t)p*NM + (size_t)row*64 + j];
  t *= norm[row];
  target[(size_t)row*64 + j] = t;
  sx[wv][j] = t;
  if (j < 16) {
    const float FREQ[8] = {1.0f, 0.316227766016838f, 0.1f, 0.0316227766016838f,
                           0.01f, 0.00316227766016838f, 0.001f, 0.000316227766016838f};
    float tt = (float)ts[row];
    float e = emb_b[j];
    #pragma unroll
    for (int k = 0; k < 8; ++k) {
      float a = tt * FREQ[k];
      e = fmaf(cosf(a), emb_w[k*16 + j], e);
      e = fmaf(sinf(a), emb_w[(8+k)*16 + j], e);
    }
    sx[wv][64 + j] = e;
  }
  __syncthreads();
  float a0 = in_b[4*j+0], a1 = in_b[4*j+1], a2 = in_b[4*j+2], a3 = in_b[4*j+3];
  #pragma unroll 8
  for (int k = 0; k < 80; ++k) {
    float xv = sx[wv][k];
    float4 w = *(const float4*)(in_w + k*256 + 4*j);
    a0 = fmaf(xv, w.x, a0);
    a1 = fmaf(xv, w.y, a1);
    a2 = fmaf(xv, w.z, a2);
    a3 = fmaf(xv, w.w, a3);
  }
  sh[wv][4*j+0] = tanhf(a0); sh[wv][4*j+1] = tanhf(a1);
  sh[wv][4*j+2] = tanhf(a2); sh[wv][4*j+3] = tanhf(a3);
  __syncthreads();
  float o = out_b[j];
  #pragma unroll 8
  for (int k = 0; k < 256; ++k) o = fmaf(sh[wv][k], out_w[k*64 + j], o);
  sa[wv][j] = o;
  __syncthreads();
  float q = bq[j], kk = bk[j], vv = bv[j];
  #pragma unroll 8
  for (int k = 0; k < 64; ++k) {
    float tv = sx[wv][k], av = sa[wv][k];
    q  = fmaf(tv, wq[k*64+j],  q);
    kk = fmaf(av, wk[k*64+j],  kk);
    vv = fmaf(av, wvw[k*64+j], vv);
  }
  // q scaled by (1/sqrt(hd)) * log2(e) so scores are in exp2 domain
  qh[(size_t)row*64+j] = (f16)(q * 0.360673760222241f);
  kh[(size_t)row*64+j] = (f16)kk;
  sv[wv][j] = vv;
  __syncthreads();
  if (threadIdx.x < 64){
    int c = threadIdx.x;
    f16x4 pk = {(f16)sv[0][c], (f16)sv[1][c], (f16)sv[2][c], (f16)sv[3][c]};
    *(f16x4*)(vt + (size_t)c*NTOT + blockIdx.x*4) = pk;
  }
}

// ---------------- Kernel 3: MFMA flash attention per-slice partials ----------
// grid (96 qblocks, 8 z-slices), block 256 = 4 waves; wave = head.
// exp2 domain; depth-2 prefetch (loads for kt+2 issued at kt).
__global__ __launch_bounds__(256) void k_attn(const f16* __restrict__ qh,
                                              const f16* __restrict__ kh,
                                              const f16* __restrict__ vt,
                                              float* __restrict__ opart,
                                              float* __restrict__ lpart){
  __shared__ f16 sK[2][64][72];   // [key][d]
  __shared__ f16 sV[2][64][72];   // [d][key]
  const int tid = threadIdx.x;
  const int h = tid >> 6;
  const int lane = tid & 63;
  const int l15 = lane & 15, quad = lane >> 4;
  const int z = blockIdx.y;
  const int q0 = blockIdx.x * 64;

  f16x4 qf[4];
  #pragma unroll
  for (int qn = 0; qn < 4; ++qn)
    qf[qn] = *(const f16x4*)(qh + (size_t)(q0 + qn*16 + l15)*64 + h*16 + quad*4);

  f32x4 accOT[4] = {{0.f,0.f,0.f,0.f},{0.f,0.f,0.f,0.f},
                    {0.f,0.f,0.f,0.f},{0.f,0.f,0.f,0.f}};
  float lsum[4] = {0.f, 0.f, 0.f, 0.f};
  const int sr = tid >> 2, scg = (tid & 3) * 16;
  const int kbase = z * 768;
  f16x8 kA0, kA1, vA0, vA1, kB0, kB1, vB0, vB1;
  auto LOADA = [&](int kt){
    const int k0 = kbase + kt*64;
    const f16* pk = kh + (size_t)(k0 + sr)*64 + scg;
    kA0 = *(const f16x8*)pk; kA1 = *(const f16x8*)(pk + 8);
    const f16* pv = vt + (size_t)sr*NTOT + k0 + scg;
    vA0 = *(const f16x8*)pv; vA1 = *(const f16x8*)(pv + 8);
  };
  auto LOADB = [&](int kt){
    const int k0 = kbase + kt*64;
    const f16* pk = kh + (size_t)(k0 + sr)*64 + scg;
    kB0 = *(const f16x8*)pk; kB1 = *(const f16x8*)(pk + 8);
    const f16* pv = vt + (size_t)sr*NTOT + k0 + scg;
    vB0 = *(const f16x8*)pv; vB1 = *(const f16x8*)(pv + 8);
  };
  auto WRA = [&](int b){
    *(f16x8*)&sK[b][sr][scg]     = kA0;
    *(f16x8*)&sK[b][sr][scg + 8] = kA1;
    *(f16x8*)&sV[b][sr][scg]     = vA0;
    *(f16x8*)&sV[b][sr][scg + 8] = vA1;
  };
  auto WRB = [&](int b){
    *(f16x8*)&sK[b][sr][scg]     = kB0;
    *(f16x8*)&sK[b][sr][scg + 8] = kB1;
    *(f16x8*)&sV[b][sr][scg]     = vB0;
    *(f16x8*)&sV[b][sr][scg + 8] = vB1;
  };
  auto COMPUTE = [&](int b){
    #pragma unroll
    for (int km = 0; km < 4; ++km){
      f16x4 kf = *(const f16x4*)&sK[b][km*16 + l15][h*16 + quad*4];
      f16x4 vf = *(const f16x4*)&sV[b][h*16 + l15][km*16 + quad*4];
      #pragma unroll
      for (int qn = 0; qn < 4; ++qn){
        f32x4 s = __builtin_amdgcn_mfma_f32_16x16x16f16(
            kf, qf[qn], (f32x4){0.f,0.f,0.f,0.f}, 0, 0, 0);
        float p0 = exp2f(fminf(s[0], 14.4269504088896f));
        float p1 = exp2f(fminf(s[1], 14.4269504088896f));
        float p2 = exp2f(fminf(s[2], 14.4269504088896f));
        float p3 = exp2f(fminf(s[3], 14.4269504088896f));
        lsum[qn] += (p0 + p1) + (p2 + p3);
        f16x2 plo = __builtin_amdgcn_cvt_pkrtz(p0, p1);
        f16x2 phi = __builtin_amdgcn_cvt_pkrtz(p2, p3);
        f16x4 pf = __builtin_shufflevector(plo, phi, 0, 1, 2, 3);
        accOT[qn] = __builtin_amdgcn_mfma_f32_16x16x16f16(vf, pf, accOT[qn], 0, 0, 0);
      }
    }
  };
  LOADA(0); LOADB(1); WRA(0);
  for (int kt2 = 0; kt2 < 12; kt2 += 2){
    if (kt2 + 2 < 12) LOADA(kt2 + 2);
    __syncthreads();
    COMPUTE(0);
    WRB(1);
    if (kt2 + 3 < 12) LOADB(kt2 + 3);
    __syncthreads();
    COMPUTE(1);
    if (kt2 + 2 < 12) WRA(0);
  }
  #pragma unroll
  for (int qn = 0; qn < 4; ++qn){
    lsum[qn] += __shfl_xor(lsum[qn], 16, 64);
    lsum[qn] += __shfl_xor(lsum[qn], 32, 64);
  }
  #pragma unroll
  for (int qn = 0; qn < 4; ++qn){
    const int row = q0 + qn*16 + l15;
    *(float4*)(opart + (size_t)z*NM + (size_t)row*64 + h*16 + quad*4) =
        make_float4(accOT[qn][0], accOT[qn][1], accOT[qn][2], accOT[qn][3]);
    if (quad == 0) lpart[((size_t)z*4 + h)*NTOT + row] = lsum[qn];
  }
}

// ------- Kernel 4: combine slices + out-proj + fuse + residual LN (fused) ----
__global__ __launch_bounds__(256) void k_out(const float* __restrict__ opart,
                                             const float* __restrict__ lpart,
                                             const float* __restrict__ target,
                                             const float* __restrict__ wo, const float* __restrict__ bo,
                                             const float* __restrict__ fuse_w, const float* __restrict__ fuse_b,
                                             const float* __restrict__ ln_g, const float* __restrict__ ln_b,
                                             float* __restrict__ out){
  __shared__ float st[4][64], sa[4][64], sao[4][64];
  int wv = threadIdx.x>>6, j = threadIdx.x&63;
  int row = blockIdx.x*4 + wv;
  int h = j >> 4;
  float osum = 0.f, L = 0.f;
  #pragma unroll
  for (int z = 0; z < 8; ++z) {
    osum += opart[(size_t)z*NM + (size_t)row*64 + j];
    L    += lpart[((size_t)z*4 + h)*NTOT + row];
  }
  sa[wv][j] = osum / L;
  st[wv][j] = target[(size_t)row*64+j];
  __syncthreads();
  float ao = bo[j];
  #pragma unroll 8
  for (int k = 0; k < 64; ++k) ao = fmaf(sa[wv][k], wo[k*64+j], ao);
  sao[wv][j] = ao;
  __syncthreads();
  float f = fuse_b[j];
  #pragma unroll 8
  for (int k = 0; k < 64; ++k) f = fmaf(st[wv][k], fuse_w[k*64+j], f);
  #pragma unroll 8
  for (int k = 0; k < 64; ++k) f = fmaf(sao[wv][k], fuse_w[(64+k)*64+j], f);
  float x = f + st[wv][j];
  float s1 = x, s2 = x*x;
  #pragma unroll
  for (int off = 32; off; off >>= 1) { s1 += __shfl_xor(s1, off, 64); s2 += __shfl_xor(s2, off, 64); }
  float mu = s1*(1.f/64.f);
  float var = s2*(1.f/64.f) - mu*mu;
  float y = (x-mu)*rsqrtf(var + 1e-5f)*ln_g[j] + ln_b[j];
  out[(size_t)row*64 + j] = y;
}

extern "C" void kernel_launch(void* const* d_in, const int* in_sizes, int n_in,
                              void* d_out, int out_size, void* d_ws, size_t ws_size,
                              hipStream_t stream) {
  const float* graph  = (const float*)d_in[0];
  const float* drug_f = (const float*)d_in[1];
  const float* dis_f  = (const float*)d_in[2];
  const int*   ts     = (const int*)d_in[3];
  const float* drug_w = (const float*)d_in[4];
  const float* dis_w  = (const float*)d_in[5];
  const float* emb_w  = (const float*)d_in[6];
  const float* emb_b  = (const float*)d_in[7];
  const float* in_w   = (const float*)d_in[8];
  const float* in_b   = (const float*)d_in[9];
  const float* out_w  = (const float*)d_in[10];
  const float* out_b  = (const float*)d_in[11];
  const float* wq     = (const float*)d_in[12];
  const float* bq     = (const float*)d_in[13];
  const float* wk     = (const float*)d_in[14];
  const float* bk     = (const float*)d_in[15];
  const float* wvw    = (const float*)d_in[16];
  const float* bv     = (const float*)d_in[17];
  const float* wo     = (const float*)d_in[18];
  const float* bo     = (const float*)d_in[19];
  const float* fuse_w = (const float*)d_in[20];
  const float* fuse_b = (const float*)d_in[21];
  const float* ln_g   = (const float*)d_in[22];
  const float* ln_b   = (const float*)d_in[23];

  float*    ws     = (float*)d_ws;
  float*    norm   = ws;                                  // floats [0..6143]
  unsigned* ready  = (unsigned*)(ws + 6656);              // 8 slice counters
  f16*      nfst   = (f16*)(ws + 8192);                   // 64*NTOT halves
  float*    target = ws + 8192 + (size_t)64*NTOT/2;       // NM floats
  f16*      qh     = (f16*)(target + NM);                 // NM halves
  f16*      kh     = (f16*)(target + NM + NM/2);          // NM halves
  f16*      vt     = (f16*)(target + NM + NM);            // NM halves
  float*    part   = target + NM + NM + NM/2;             // 8*NM floats
  float*    opart  = part + (size_t)8*NM;                 // 8*NM floats
  float*    lpart  = opart + (size_t)8*NM;                // 8*4*NTOT floats

  hipMemsetAsync((void*)ready, 0, 32, stream);            // zero slice counters
  k_dg<<<768, 256, 0, stream>>>(graph, drug_f, dis_f, drug_w, dis_w,
                                norm, nfst, part, ready);
  k_node2<<<1536, 256, 0, stream>>>(part, norm, ts, emb_w, emb_b, in_w, in_b,
                                    out_w, out_b, wq, bq, wk, bk, wvw, bv,
                                    target, qh, kh, vt);
  k_attn<<<dim3(96, 8), 256, 0, stream>>>(qh, kh, vt, opart, lpart);
  k_out<<<1536, 256, 0, stream>>>(opart, lpart, target, wo, bo, fuse_w, fuse_b,
                                  ln_g, ln_b, (float*)d_out);
}

// Round 9
// 403.950 us; speedup vs baseline: 1.2677x; 1.2677x over previous
//
#include <hip/hip_runtime.h>
#include <cstdint>
#include <cstddef>

#define NTOT 6144
#define NDRUG 3072
#define NM (NTOT*64)
#define NSLICE 16
#define KSLICE 384
#define NKT 6

typedef __fp16 f16;
typedef __attribute__((ext_vector_type(2))) __fp16 f16x2;
typedef __attribute__((ext_vector_type(4))) __fp16 f16x4;
typedef __attribute__((ext_vector_type(8))) __fp16 f16x8;
typedef __attribute__((ext_vector_type(4))) float f32x4;

__device__ __forceinline__ f16x8 pack8(float4 a, float4 b){
  f16x2 p0 = __builtin_amdgcn_cvt_pkrtz(a.x, a.y);
  f16x2 p1 = __builtin_amdgcn_cvt_pkrtz(a.z, a.w);
  f16x2 p2 = __builtin_amdgcn_cvt_pkrtz(b.x, b.y);
  f16x2 p3 = __builtin_amdgcn_cvt_pkrtz(b.z, b.w);
  f16x4 lo = __builtin_shufflevector(p0, p1, 0, 1, 2, 3);
  f16x4 hi = __builtin_shufflevector(p2, p3, 0, 1, 2, 3);
  return __builtin_shufflevector(lo, hi, 0, 1, 2, 3, 4, 5, 6, 7);
}

// ------- Kernel 1: rowsum -> norm; nfs^T fp16 -------------------------------
__global__ __launch_bounds__(256) void k_deg(const float* __restrict__ g,
                                             const float* __restrict__ drug_f,
                                             const float* __restrict__ dis_f,
                                             const float* __restrict__ drug_w,
                                             const float* __restrict__ dis_w,
                                             float* __restrict__ norm,
                                             f16* __restrict__ nfst){
  __shared__ float sx[4][64];
  __shared__ float snf[4][64];
  int wv = threadIdx.x >> 6, j = threadIdx.x & 63;
  int row = blockIdx.x*4 + wv;
  const float4* p = (const float4*)(g + (size_t)row * NTOT);
  float s = 0.f;
  #pragma unroll
  for (int it = 0; it < 24; ++it) {
    float4 u = p[it*64 + j];
    s += (u.x + u.y) + (u.z + u.w);
  }
  #pragma unroll
  for (int off = 32; off; off >>= 1) s += __shfl_xor(s, off, 64);
  float nrm = rsqrtf(fmaxf(s, 1.0f));
  if (j == 0) norm[row] = nrm;

  const float* x; const float* W;
  if (row < NDRUG){ x = drug_f + (size_t)row*64; W = drug_w; }
  else            { x = dis_f + (size_t)(row-NDRUG)*64; W = dis_w; }
  sx[wv][j] = x[j];
  __syncthreads();
  float acc = 0.f;
  #pragma unroll 8
  for (int k = 0; k < 64; ++k) acc = fmaf(sx[wv][k], W[k*64+j], acc);
  snf[wv][j] = acc * nrm;
  __syncthreads();
  if (threadIdx.x < 64){
    int c = threadIdx.x;
    f16x4 pk = {(f16)snf[0][c], (f16)snf[1][c], (f16)snf[2][c], (f16)snf[3][c]};
    *(f16x4*)(nfst + (size_t)c*NTOT + blockIdx.x*4) = pk;
  }
}

// ---------------- Kernel 2: MFMA split-K GEMM: part[z] = graph_tile @ nfs ---
// grid (96, 16), block 256 = 4 waves; K-range 384/slice, 6 kt of 64.
// SINGLE-buffer LDS (18.4 KB -> 8 blocks/CU LDS cap) + register-carried
// next-tile loads. TLP (target 5-6 blocks/CU) hides latency instead of dbuf.
__global__ __launch_bounds__(256) void k_gemm(const float* __restrict__ graph,
                                              const f16* __restrict__ nfst,
                                              float* __restrict__ part){
  __shared__ f16 sA[64][72];
  __shared__ f16 sB[64][72];
  const int tid = threadIdx.x;
  const int lane = tid & 63, w = tid >> 6;
  const int l15 = lane & 15, quad = lane >> 4;
  const int row0 = blockIdx.x * 64;
  const int kbase = blockIdx.y * KSLICE;
  const int sr = tid >> 2, scg = (tid & 3) * 16;

  f32x4 acc[4] = {{0.f,0.f,0.f,0.f},{0.f,0.f,0.f,0.f},
                  {0.f,0.f,0.f,0.f},{0.f,0.f,0.f,0.f}};
  float4 a0, a1, a2, a3;
  f16x8 b0, b1;
  auto LOADT = [&](int kt){
    const float4* pa = (const float4*)(graph + (size_t)(row0 + sr)*NTOT + kbase + kt*64 + scg);
    a0 = pa[0]; a1 = pa[1]; a2 = pa[2]; a3 = pa[3];
    const f16* pb = nfst + (size_t)sr*NTOT + kbase + kt*64 + scg;
    b0 = *(const f16x8*)pb; b1 = *(const f16x8*)(pb + 8);
  };
  auto WRITET = [&](){
    *(f16x8*)&sA[sr][scg]     = pack8(a0, a1);
    *(f16x8*)&sA[sr][scg + 8] = pack8(a2, a3);
    *(f16x8*)&sB[sr][scg]     = b0;
    *(f16x8*)&sB[sr][scg + 8] = b1;
  };
  LOADT(0);
  WRITET();
  __syncthreads();
  for (int kt = 0; kt < NKT; ++kt){
    if (kt + 1 < NKT) LOADT(kt + 1);
    #pragma unroll
    for (int k16 = 0; k16 < 4; ++k16){
      f16x4 af = *(const f16x4*)&sA[w*16 + l15][k16*16 + quad*4];
      #pragma unroll
      for (int nt = 0; nt < 4; ++nt){
        f16x4 bf = *(const f16x4*)&sB[nt*16 + l15][k16*16 + quad*4];
        acc[nt] = __builtin_amdgcn_mfma_f32_16x16x16f16(af, bf, acc[nt], 0, 0, 0);
      }
    }
    if (kt + 1 < NKT){
      __syncthreads();   // all reads of current tile done
      WRITET();
      __syncthreads();   // next tile visible
    }
  }
  float* dst = part + (size_t)blockIdx.y * NM;
  #pragma unroll
  for (int nt = 0; nt < 4; ++nt){
    #pragma unroll
    for (int r = 0; r < 4; ++r){
      int row = row0 + w*16 + quad*4 + r;
      dst[(size_t)row*64 + nt*16 + l15] = acc[nt][r];
    }
  }
}

// ------- Kernel 3: finish + time-emb MLP + qkv (fused) -----------------------
// q pre-scaled by 0.25*log2(e) so attention can use native exp2.
__global__ __launch_bounds__(256) void k_node2(const float* __restrict__ part,
                                               const float* __restrict__ norm,
                                               const int* __restrict__ ts,
                                               const float* __restrict__ emb_w,
                                               const float* __restrict__ emb_b,
                                               const float* __restrict__ in_w,
                                               const float* __restrict__ in_b,
                                               const float* __restrict__ out_w,
                                               const float* __restrict__ out_b,
                                               const float* __restrict__ wq, const float* __restrict__ bq,
                                               const float* __restrict__ wk, const float* __restrict__ bk,
                                               const float* __restrict__ wvw, const float* __restrict__ bv,
                                               float* __restrict__ target,
                                               f16* __restrict__ qh, f16* __restrict__ kh,
                                               f16* __restrict__ vt){
  __shared__ float sx[4][80];    // [0..63]=target row, [64..79]=time emb
  __shared__ float sh[4][256];
  __shared__ float sa[4][64];    // aux row (LDS only)
  __shared__ float sv[4][64];    // v row (for transpose)
  int wv = threadIdx.x>>6, j = threadIdx.x&63;
  int row = blockIdx.x*4 + wv;

  float t = 0.f;
  #pragma unroll
  for (int p = 0; p < NSLICE; ++p) t += part[(size_t)p*NM + (size_t)row*64 + j];
  t *= norm[row];
  target[(size_t)row*64 + j] = t;
  sx[wv][j] = t;
  if (j < 16) {
    const float FREQ[8] = {1.0f, 0.316227766016838f, 0.1f, 0.0316227766016838f,
                           0.01f, 0.00316227766016838f, 0.001f, 0.000316227766016838f};
    float tt = (float)ts[row];
    float e = emb_b[j];
    #pragma unroll
    for (int k = 0; k < 8; ++k) {
      float a = tt * FREQ[k];
      e = fmaf(cosf(a), emb_w[k*16 + j], e);
      e = fmaf(sinf(a), emb_w[(8+k)*16 + j], e);
    }
    sx[wv][64 + j] = e;
  }
  __syncthreads();
  float a0 = in_b[4*j+0], a1 = in_b[4*j+1], a2 = in_b[4*j+2], a3 = in_b[4*j+3];
  #pragma unroll 8
  for (int k = 0; k < 80; ++k) {
    float xv = sx[wv][k];
    float4 w = *(const float4*)(in_w + k*256 + 4*j);
    a0 = fmaf(xv, w.x, a0);
    a1 = fmaf(xv, w.y, a1);
    a2 = fmaf(xv, w.z, a2);
    a3 = fmaf(xv, w.w, a3);
  }
  sh[wv][4*j+0] = tanhf(a0); sh[wv][4*j+1] = tanhf(a1);
  sh[wv][4*j+2] = tanhf(a2); sh[wv][4*j+3] = tanhf(a3);
  __syncthreads();
  float o = out_b[j];
  #pragma unroll 8
  for (int k = 0; k < 256; ++k) o = fmaf(sh[wv][k], out_w[k*64 + j], o);
  sa[wv][j] = o;
  __syncthreads();
  float q = bq[j], kk = bk[j], vv = bv[j];
  #pragma unroll 8
  for (int k = 0; k < 64; ++k) {
    float tv = sx[wv][k], av = sa[wv][k];
    q  = fmaf(tv, wq[k*64+j],  q);
    kk = fmaf(av, wk[k*64+j],  kk);
    vv = fmaf(av, wvw[k*64+j], vv);
  }
  // q scaled by (1/sqrt(hd)) * log2(e) so scores are in exp2 domain
  qh[(size_t)row*64+j] = (f16)(q * 0.360673760222241f);
  kh[(size_t)row*64+j] = (f16)kk;
  sv[wv][j] = vv;
  __syncthreads();
  if (threadIdx.x < 64){
    int c = threadIdx.x;
    f16x4 pk = {(f16)sv[0][c], (f16)sv[1][c], (f16)sv[2][c], (f16)sv[3][c]};
    *(f16x4*)(vt + (size_t)c*NTOT + blockIdx.x*4) = pk;
  }
}

// ---------------- Kernel 4: MFMA flash attention per-slice partials ----------
// grid (96 qblocks, 16 z-slices), block 256 = 4 waves; wave = head.
// K-range 384/slice, 6 kt. SINGLE-buffer LDS + register-carried loads
// (same TLP rationale as k_gemm). exp2 domain.
__global__ __launch_bounds__(256) void k_attn(const f16* __restrict__ qh,
                                              const f16* __restrict__ kh,
                                              const f16* __restrict__ vt,
                                              float* __restrict__ opart,
                                              float* __restrict__ lpart){
  __shared__ f16 sK[64][72];   // [key][d]
  __shared__ f16 sV[64][72];   // [d][key]
  const int tid = threadIdx.x;
  const int h = tid >> 6;
  const int lane = tid & 63;
  const int l15 = lane & 15, quad = lane >> 4;
  const int z = blockIdx.y;
  const int q0 = blockIdx.x * 64;

  f16x4 qf[4];
  #pragma unroll
  for (int qn = 0; qn < 4; ++qn)
    qf[qn] = *(const f16x4*)(qh + (size_t)(q0 + qn*16 + l15)*64 + h*16 + quad*4);

  f32x4 accOT[4] = {{0.f,0.f,0.f,0.f},{0.f,0.f,0.f,0.f},
                    {0.f,0.f,0.f,0.f},{0.f,0.f,0.f,0.f}};
  float lsum[4] = {0.f, 0.f, 0.f, 0.f};
  const int sr = tid >> 2, scg = (tid & 3) * 16;
  const int kbase = z * KSLICE;
  f16x8 k0r, k1r, v0r, v1r;
  auto LOADT = [&](int kt){
    const int k0 = kbase + kt*64;
    const f16* pk = kh + (size_t)(k0 + sr)*64 + scg;
    k0r = *(const f16x8*)pk; k1r = *(const f16x8*)(pk + 8);
    const f16* pv = vt + (size_t)sr*NTOT + k0 + scg;
    v0r = *(const f16x8*)pv; v1r = *(const f16x8*)(pv + 8);
  };
  auto WRITET = [&](){
    *(f16x8*)&sK[sr][scg]     = k0r;
    *(f16x8*)&sK[sr][scg + 8] = k1r;
    *(f16x8*)&sV[sr][scg]     = v0r;
    *(f16x8*)&sV[sr][scg + 8] = v1r;
  };
  LOADT(0);
  WRITET();
  __syncthreads();
  for (int kt = 0; kt < NKT; ++kt){
    if (kt + 1 < NKT) LOADT(kt + 1);
    #pragma unroll
    for (int km = 0; km < 4; ++km){
      f16x4 kf = *(const f16x4*)&sK[km*16 + l15][h*16 + quad*4];
      f16x4 vf = *(const f16x4*)&sV[h*16 + l15][km*16 + quad*4];
      #pragma unroll
      for (int qn = 0; qn < 4; ++qn){
        f32x4 s = __builtin_amdgcn_mfma_f32_16x16x16f16(
            kf, qf[qn], (f32x4){0.f,0.f,0.f,0.f}, 0, 0, 0);
        float p0 = exp2f(fminf(s[0], 14.4269504088896f));
        float p1 = exp2f(fminf(s[1], 14.4269504088896f));
        float p2 = exp2f(fminf(s[2], 14.4269504088896f));
        float p3 = exp2f(fminf(s[3], 14.4269504088896f));
        lsum[qn] += (p0 + p1) + (p2 + p3);
        f16x2 plo = __builtin_amdgcn_cvt_pkrtz(p0, p1);
        f16x2 phi = __builtin_amdgcn_cvt_pkrtz(p2, p3);
        f16x4 pf = __builtin_shufflevector(plo, phi, 0, 1, 2, 3);
        accOT[qn] = __builtin_amdgcn_mfma_f32_16x16x16f16(vf, pf, accOT[qn], 0, 0, 0);
      }
    }
    if (kt + 1 < NKT){
      __syncthreads();
      WRITET();
      __syncthreads();
    }
  }
  #pragma unroll
  for (int qn = 0; qn < 4; ++qn){
    lsum[qn] += __shfl_xor(lsum[qn], 16, 64);
    lsum[qn] += __shfl_xor(lsum[qn], 32, 64);
  }
  #pragma unroll
  for (int qn = 0; qn < 4; ++qn){
    const int row = q0 + qn*16 + l15;
    *(float4*)(opart + (size_t)z*NM + (size_t)row*64 + h*16 + quad*4) =
        make_float4(accOT[qn][0], accOT[qn][1], accOT[qn][2], accOT[qn][3]);
    if (quad == 0) lpart[((size_t)z*4 + h)*NTOT + row] = lsum[qn];
  }
}

// ------- Kernel 5: combine slices + out-proj + fuse + residual LN (fused) ----
__global__ __launch_bounds__(256) void k_out(const float* __restrict__ opart,
                                             const float* __restrict__ lpart,
                                             const float* __restrict__ target,
                                             const float* __restrict__ wo, const float* __restrict__ bo,
                                             const float* __restrict__ fuse_w, const float* __restrict__ fuse_b,
                                             const float* __restrict__ ln_g, const float* __restrict__ ln_b,
                                             float* __restrict__ out){
  __shared__ float st[4][64], sa[4][64], sao[4][64];
  int wv = threadIdx.x>>6, j = threadIdx.x&63;
  int row = blockIdx.x*4 + wv;
  int h = j >> 4;
  float osum = 0.f, L = 0.f;
  #pragma unroll
  for (int z = 0; z < NSLICE; ++z) {
    osum += opart[(size_t)z*NM + (size_t)row*64 + j];
    L    += lpart[((size_t)z*4 + h)*NTOT + row];
  }
  sa[wv][j] = osum / L;
  st[wv][j] = target[(size_t)row*64+j];
  __syncthreads();
  float ao = bo[j];
  #pragma unroll 8
  for (int k = 0; k < 64; ++k) ao = fmaf(sa[wv][k], wo[k*64+j], ao);
  sao[wv][j] = ao;
  __syncthreads();
  float f = fuse_b[j];
  #pragma unroll 8
  for (int k = 0; k < 64; ++k) f = fmaf(st[wv][k], fuse_w[k*64+j], f);
  #pragma unroll 8
  for (int k = 0; k < 64; ++k) f = fmaf(sao[wv][k], fuse_w[(64+k)*64+j], f);
  float x = f + st[wv][j];
  float s1 = x, s2 = x*x;
  #pragma unroll
  for (int off = 32; off; off >>= 1) { s1 += __shfl_xor(s1, off, 64); s2 += __shfl_xor(s2, off, 64); }
  float mu = s1*(1.f/64.f);
  float var = s2*(1.f/64.f) - mu*mu;
  float y = (x-mu)*rsqrtf(var + 1e-5f)*ln_g[j] + ln_b[j];
  out[(size_t)row*64 + j] = y;
}

extern "C" void kernel_launch(void* const* d_in, const int* in_sizes, int n_in,
                              void* d_out, int out_size, void* d_ws, size_t ws_size,
                              hipStream_t stream) {
  const float* graph  = (const float*)d_in[0];
  const float* drug_f = (const float*)d_in[1];
  const float* dis_f  = (const float*)d_in[2];
  const int*   ts     = (const int*)d_in[3];
  const float* drug_w = (const float*)d_in[4];
  const float* dis_w  = (const float*)d_in[5];
  const float* emb_w  = (const float*)d_in[6];
  const float* emb_b  = (const float*)d_in[7];
  const float* in_w   = (const float*)d_in[8];
  const float* in_b   = (const float*)d_in[9];
  const float* out_w  = (const float*)d_in[10];
  const float* out_b  = (const float*)d_in[11];
  const float* wq     = (const float*)d_in[12];
  const float* bq     = (const float*)d_in[13];
  const float* wk     = (const float*)d_in[14];
  const float* bk     = (const float*)d_in[15];
  const float* wvw    = (const float*)d_in[16];
  const float* bv     = (const float*)d_in[17];
  const float* wo     = (const float*)d_in[18];
  const float* bo     = (const float*)d_in[19];
  const float* fuse_w = (const float*)d_in[20];
  const float* fuse_b = (const float*)d_in[21];
  const float* ln_g   = (const float*)d_in[22];
  const float* ln_b   = (const float*)d_in[23];

  float* ws     = (float*)d_ws;
  float* norm   = ws;                                  // 8192 floats (6144 used)
  f16*   nfst   = (f16*)(ws + 8192);                   // 64*NTOT halves
  float* target = ws + 8192 + (size_t)64*NTOT/2;       // NM floats
  f16*   qh     = (f16*)(target + NM);                 // NM halves
  f16*   kh     = (f16*)(target + NM + NM/2);          // NM halves
  f16*   vt     = (f16*)(target + NM + NM);            // NM halves
  float* part   = target + NM + NM + NM/2;             // NSLICE*NM floats
  float* opart  = part + (size_t)NSLICE*NM;            // NSLICE*NM floats
  float* lpart  = opart + (size_t)NSLICE*NM;           // NSLICE*4*NTOT floats

  k_deg<<<1536, 256, 0, stream>>>(graph, drug_f, dis_f, drug_w, dis_w, norm, nfst);
  k_gemm<<<dim3(96, NSLICE), 256, 0, stream>>>(graph, nfst, part);
  k_node2<<<1536, 256, 0, stream>>>(part, norm, ts, emb_w, emb_b, in_w, in_b,
                                    out_w, out_b, wq, bq, wk, bk, wvw, bv,
                                    target, qh, kh, vt);
  k_attn<<<dim3(96, NSLICE), 256, 0, stream>>>(qh, kh, vt, opart, lpart);
  k_out<<<1536, 256, 0, stream>>>(opart, lpart, target, wo, bo, fuse_w, fuse_b,
                                  ln_g, ln_b, (float*)d_out);
}